// Round 1
// baseline (428.175 us; speedup 1.0000x reference)
//
#include <hip/hip_runtime.h>

// MLoss: masked box-MSE + face-BCE + background-BCE over [B=2048, N=2704, C=5].
// Memory-bound reduction: 221 MB read once -> ~35 us floor at 6.3 TB/s.

#define BLOCK 256
#define LOG_CLAMP -100.0f
#define THRESH 0.5f

__device__ __forceinline__ float clogf(float v) {
    return fmaxf(logf(v), LOG_CLAMP);
}

// ws layout: [0]=sum_sq (double), [1]=sum_bce (double), [2]=sum_bg (double),
//            [3]=face_count (unsigned long long)
__global__ __launch_bounds__(BLOCK) void mloss_reduce(
    const float* __restrict__ x, const float* __restrict__ y,
    double* __restrict__ ws, long long n_units)
{
    long long u = (long long)blockIdx.x * BLOCK + threadIdx.x;

    float s_sq = 0.0f, s_bce = 0.0f, s_bg = 0.0f;
    unsigned int s_cnt = 0;

    if (u < n_units) {
        // Each unit = 4 cells = 20 contiguous floats; byte offset u*80 is 16B aligned.
        const float4* x4 = (const float4*)(x + u * 20);
        const float4* y4 = (const float4*)(y + u * 20);
        float fx[20], fy[20];
        #pragma unroll
        for (int i = 0; i < 5; ++i) {
            ((float4*)fx)[i] = x4[i];
            ((float4*)fy)[i] = y4[i];
        }
        #pragma unroll
        for (int c = 0; c < 4; ++c) {
            const int base = c * 5;
            const float p = fx[base];
            const float t = fy[base];
            const bool mask = t > THRESH;

            float sq = 0.0f;
            #pragma unroll
            for (int j = 1; j < 5; ++j) {
                const float d = fx[base + j] - fy[base + j];
                sq = fmaf(d, d, sq);
            }
            const float lp  = clogf(p);
            const float l1p = clogf(1.0f - p);
            if (mask) {
                s_sq  += sq;
                s_bce += -(t * lp + (1.0f - t) * l1p);
                s_cnt += 1u;
            } else {
                s_bg  += -l1p;
            }
        }
    }

    // Wave-64 butterfly reduce
    #pragma unroll
    for (int off = 32; off > 0; off >>= 1) {
        s_sq  += __shfl_down(s_sq,  off, 64);
        s_bce += __shfl_down(s_bce, off, 64);
        s_bg  += __shfl_down(s_bg,  off, 64);
        s_cnt += __shfl_down(s_cnt, off, 64);
    }

    __shared__ float l_sq[BLOCK / 64], l_bce[BLOCK / 64], l_bg[BLOCK / 64];
    __shared__ unsigned int l_cnt[BLOCK / 64];
    const int wave = threadIdx.x >> 6;
    const int lane = threadIdx.x & 63;
    if (lane == 0) {
        l_sq[wave] = s_sq; l_bce[wave] = s_bce; l_bg[wave] = s_bg; l_cnt[wave] = s_cnt;
    }
    __syncthreads();
    if (threadIdx.x == 0) {
        float t_sq = 0.0f, t_bce = 0.0f, t_bg = 0.0f;
        unsigned int t_cnt = 0u;
        #pragma unroll
        for (int w = 0; w < BLOCK / 64; ++w) {
            t_sq += l_sq[w]; t_bce += l_bce[w]; t_bg += l_bg[w]; t_cnt += l_cnt[w];
        }
        atomicAdd(&ws[0], (double)t_sq);
        atomicAdd(&ws[1], (double)t_bce);
        atomicAdd(&ws[2], (double)t_bg);
        atomicAdd((unsigned long long*)&ws[3], (unsigned long long)t_cnt);
    }
}

// Single-thread finalize; also mops up any tail cells not covered by 4-cell units.
__global__ void mloss_final(const float* __restrict__ x, const float* __restrict__ y,
                            const double* __restrict__ ws, float* __restrict__ out,
                            long long cell_start, long long n_cells)
{
    double s_sq  = ws[0];
    double s_bce = ws[1];
    double s_bg  = ws[2];
    double face  = (double)((const unsigned long long*)ws)[3];

    for (long long c = cell_start; c < n_cells; ++c) {
        const float p = x[c * 5];
        const float t = y[c * 5];
        float sq = 0.0f;
        for (int j = 1; j < 5; ++j) {
            const float d = x[c * 5 + j] - y[c * 5 + j];
            sq = fmaf(d, d, sq);
        }
        const float lp  = clogf(p);
        const float l1p = clogf(1.0f - p);
        if (t > THRESH) {
            s_sq += (double)sq;
            s_bce += (double)(-(t * lp + (1.0f - t) * l1p));
            face += 1.0;
        } else {
            s_bg += (double)(-l1p);
        }
    }

    const double bg    = (double)n_cells - face;
    const double scale = 1.0 + 1.0 / face;
    const double r = scale * s_sq / (face * 4.0) + scale * s_bce / face + s_bg / bg;
    *out = (float)r;
}

extern "C" void kernel_launch(void* const* d_in, const int* in_sizes, int n_in,
                              void* d_out, int out_size, void* d_ws, size_t ws_size,
                              hipStream_t stream) {
    const float* x = (const float*)d_in[0];
    const float* y = (const float*)d_in[1];
    float* out = (float*)d_out;
    double* ws = (double*)d_ws;

    const long long n_elems = (long long)in_sizes[0];   // B*N*5
    const long long n_cells = n_elems / 5;              // B*N
    const long long n_units = n_cells / 4;              // 4 cells per thread
    const long long tail    = n_units * 4;              // first uncovered cell

    hipMemsetAsync(d_ws, 0, 4 * sizeof(double), stream);

    const int blocks = (int)((n_units + BLOCK - 1) / BLOCK);
    mloss_reduce<<<blocks, BLOCK, 0, stream>>>(x, y, ws, n_units);
    mloss_final<<<1, 1, 0, stream>>>(x, y, ws, out, tail, n_cells);
}

// Round 2
// 427.043 us; speedup vs baseline: 1.0026x; 1.0026x over previous
//
#include <hip/hip_runtime.h>

// MLoss: masked box-MSE + face-BCE + background-BCE over [B=2048, N=2704, C=5].
// Memory-bound: 221 MB read once -> ~35 us floor at 6.3 TB/s.
//
// R1: coalesced float4 global loads -> padded LDS transpose -> per-thread
// 20-float (4-cell) units. R0's direct per-cell loads had 80B/lane stride
// (5x cache-line request amplification, VGPR-starved serial loads) -> 275 us.

#define BLOCK 256
#define CPT 4                              // cells per thread
#define FPT (CPT * 5)                      // 20 floats per thread
#define F4PT (FPT / 4)                     // 5 float4 per thread per input
#define F4_PER_BLOCK (BLOCK * F4PT)        // 1280 float4s per block per input
#define PAD_STRIDE (FPT + 1)               // 21: odd -> conflict-free LDS reads
#define LDS_FLOATS (BLOCK * PAD_STRIDE)    // 5376 floats = 21504 B per input

#define LOG_CLAMP -100.0f
#define THRESH 0.5f

__device__ __forceinline__ float clogf(float v) {
    return fmaxf(logf(v), LOG_CLAMP);
}

// ws layout: [0]=sum_sq (double), [1]=sum_bce (double), [2]=sum_bg (double),
//            [3]=face_count (unsigned long long)
__global__ __launch_bounds__(BLOCK) void mloss_reduce(
    const float* __restrict__ x, const float* __restrict__ y,
    double* __restrict__ ws)
{
    __shared__ float lx[LDS_FLOATS];
    __shared__ float ly[LDS_FLOATS];

    // ---- Stage: coalesced float4 loads -> padded LDS ----
    const long long base_f4 = (long long)blockIdx.x * F4_PER_BLOCK;
    const float4* gx = (const float4*)x + base_f4;
    const float4* gy = (const float4*)y + base_f4;

    float4 vx[F4PT], vy[F4PT];
    #pragma unroll
    for (int k = 0; k < F4PT; ++k) {
        const int i4 = threadIdx.x + k * BLOCK;
        vx[k] = gx[i4];
        vy[k] = gy[i4];
    }
    #pragma unroll
    for (int k = 0; k < F4PT; ++k) {
        const int i4 = threadIdx.x + k * BLOCK;
        // A float4 never straddles a 20-float unit boundary (4*i4 % 20 <= 16),
        // so the pad shift is uniform across its 4 elements: i4/5.
        const int p = 4 * i4 + i4 / 5;
        lx[p + 0] = vx[k].x; lx[p + 1] = vx[k].y; lx[p + 2] = vx[k].z; lx[p + 3] = vx[k].w;
        ly[p + 0] = vy[k].x; ly[p + 1] = vy[k].y; ly[p + 2] = vy[k].z; ly[p + 3] = vy[k].w;
    }
    __syncthreads();

    // ---- Compute: each thread owns 4 cells = 20 floats at stride-21 base ----
    const float* mx = &lx[threadIdx.x * PAD_STRIDE];
    const float* my = &ly[threadIdx.x * PAD_STRIDE];

    float s_sq = 0.0f, s_bce = 0.0f, s_bg = 0.0f;
    unsigned int s_cnt = 0u;

    #pragma unroll
    for (int c = 0; c < CPT; ++c) {
        const int b = c * 5;
        const float p = mx[b];
        const float t = my[b];
        float sq = 0.0f;
        #pragma unroll
        for (int j = 1; j < 5; ++j) {
            const float d = mx[b + j] - my[b + j];
            sq = fmaf(d, d, sq);
        }
        const float lp  = clogf(p);
        const float l1p = clogf(1.0f - p);
        const bool mask = t > THRESH;
        const float bce = -(t * lp + (1.0f - t) * l1p);
        s_sq  += mask ? sq : 0.0f;
        s_bce += mask ? bce : 0.0f;
        s_bg  += mask ? 0.0f : -l1p;
        s_cnt += mask ? 1u : 0u;
    }

    // ---- Wave-64 butterfly reduce ----
    #pragma unroll
    for (int off = 32; off > 0; off >>= 1) {
        s_sq  += __shfl_down(s_sq,  off, 64);
        s_bce += __shfl_down(s_bce, off, 64);
        s_bg  += __shfl_down(s_bg,  off, 64);
        s_cnt += __shfl_down(s_cnt, off, 64);
    }

    __shared__ float r_sq[BLOCK / 64], r_bce[BLOCK / 64], r_bg[BLOCK / 64];
    __shared__ unsigned int r_cnt[BLOCK / 64];
    const int wave = threadIdx.x >> 6;
    const int lane = threadIdx.x & 63;
    if (lane == 0) {
        r_sq[wave] = s_sq; r_bce[wave] = s_bce; r_bg[wave] = s_bg; r_cnt[wave] = s_cnt;
    }
    __syncthreads();
    if (threadIdx.x == 0) {
        float t_sq = 0.0f, t_bce = 0.0f, t_bg = 0.0f;
        unsigned int t_cnt = 0u;
        #pragma unroll
        for (int w = 0; w < BLOCK / 64; ++w) {
            t_sq += r_sq[w]; t_bce += r_bce[w]; t_bg += r_bg[w]; t_cnt += r_cnt[w];
        }
        atomicAdd(&ws[0], (double)t_sq);
        atomicAdd(&ws[1], (double)t_bce);
        atomicAdd(&ws[2], (double)t_bg);
        atomicAdd((unsigned long long*)&ws[3], (unsigned long long)t_cnt);
    }
}

// Single-thread finalize; also mops up tail cells not covered by full blocks.
__global__ void mloss_final(const float* __restrict__ x, const float* __restrict__ y,
                            const double* __restrict__ ws, float* __restrict__ out,
                            long long cell_start, long long n_cells)
{
    double s_sq  = ws[0];
    double s_bce = ws[1];
    double s_bg  = ws[2];
    double face  = (double)((const unsigned long long*)ws)[3];

    for (long long c = cell_start; c < n_cells; ++c) {
        const float p = x[c * 5];
        const float t = y[c * 5];
        float sq = 0.0f;
        for (int j = 1; j < 5; ++j) {
            const float d = x[c * 5 + j] - y[c * 5 + j];
            sq = fmaf(d, d, sq);
        }
        const float lp  = clogf(p);
        const float l1p = clogf(1.0f - p);
        if (t > THRESH) {
            s_sq += (double)sq;
            s_bce += (double)(-(t * lp + (1.0f - t) * l1p));
            face += 1.0;
        } else {
            s_bg += (double)(-l1p);
        }
    }

    const double bg    = (double)n_cells - face;
    const double scale = 1.0 + 1.0 / face;
    const double r = scale * s_sq / (face * 4.0) + scale * s_bce / face + s_bg / bg;
    *out = (float)r;
}

extern "C" void kernel_launch(void* const* d_in, const int* in_sizes, int n_in,
                              void* d_out, int out_size, void* d_ws, size_t ws_size,
                              hipStream_t stream) {
    const float* x = (const float*)d_in[0];
    const float* y = (const float*)d_in[1];
    float* out = (float*)d_out;
    double* ws = (double*)d_ws;

    const long long n_elems = (long long)in_sizes[0];           // B*N*5
    const long long n_cells = n_elems / 5;                      // B*N
    const long long cells_per_block = (long long)BLOCK * CPT;   // 1024
    const long long full_blocks = n_cells / cells_per_block;    // 5408 for ref shape
    const long long covered = full_blocks * cells_per_block;    // == n_cells here

    hipMemsetAsync(d_ws, 0, 4 * sizeof(double), stream);

    mloss_reduce<<<(int)full_blocks, BLOCK, 0, stream>>>(x, y, ws);
    mloss_final<<<1, 1, 0, stream>>>(x, y, ws, out, covered, n_cells);
}

// Round 3
// 233.320 us; speedup vs baseline: 1.8351x; 1.8303x over previous
//
#include <hip/hip_runtime.h>

// MLoss: masked box-MSE + face-BCE + background-BCE over [B=2048, N=2704, C=5].
// Memory-bound: 221 MB read once -> ~35 us floor at 6.3 TB/s.
//
// R1: coalesced float4 -> padded LDS -> 4-cell units (access pattern fixed).
// R2: R0 and R1 both sat at 274 us regardless of access pattern; a replay with
//     inputs fully cache-resident ALSO took 274 us => bound by 21.6k f64
//     atomicAdds to one cache line (~30 cyc each serialized ~= 270 us).
//     Fix: atomic-free two-stage reduction (per-block float4 partials).

#define BLOCK 256
#define CPT 4                              // cells per thread
#define FPT (CPT * 5)                      // 20 floats per thread
#define F4PT (FPT / 4)                     // 5 float4 per thread per input
#define F4_PER_BLOCK (BLOCK * F4PT)        // 1280 float4s per block per input
#define PAD_STRIDE (FPT + 1)               // 21: odd -> conflict-free LDS reads
#define LDS_FLOATS (BLOCK * PAD_STRIDE)    // 5376 floats = 21504 B per input

#define LOG_CLAMP -100.0f
#define THRESH 0.5f

__device__ __forceinline__ float clogf(float v) {
    return fmaxf(logf(v), LOG_CLAMP);
}

// Stage 1: per-block partials, no atomics.
// partials[b] = {sum_sq, sum_bce, sum_bg, face_count} for block b.
__global__ __launch_bounds__(BLOCK) void mloss_reduce(
    const float* __restrict__ x, const float* __restrict__ y,
    float4* __restrict__ partials)
{
    __shared__ float lx[LDS_FLOATS];
    __shared__ float ly[LDS_FLOATS];

    // ---- Stage: coalesced float4 loads -> padded LDS ----
    const long long base_f4 = (long long)blockIdx.x * F4_PER_BLOCK;
    const float4* gx = (const float4*)x + base_f4;
    const float4* gy = (const float4*)y + base_f4;

    float4 vx[F4PT], vy[F4PT];
    #pragma unroll
    for (int k = 0; k < F4PT; ++k) {
        const int i4 = threadIdx.x + k * BLOCK;
        vx[k] = gx[i4];
        vy[k] = gy[i4];
    }
    #pragma unroll
    for (int k = 0; k < F4PT; ++k) {
        const int i4 = threadIdx.x + k * BLOCK;
        // A float4 never straddles a 20-float unit boundary (4*i4 % 20 <= 16),
        // so the pad shift is uniform across its 4 elements: i4/5.
        const int p = 4 * i4 + i4 / 5;
        lx[p + 0] = vx[k].x; lx[p + 1] = vx[k].y; lx[p + 2] = vx[k].z; lx[p + 3] = vx[k].w;
        ly[p + 0] = vy[k].x; ly[p + 1] = vy[k].y; ly[p + 2] = vy[k].z; ly[p + 3] = vy[k].w;
    }
    __syncthreads();

    // ---- Compute: each thread owns 4 cells = 20 floats at stride-21 base ----
    const float* mx = &lx[threadIdx.x * PAD_STRIDE];
    const float* my = &ly[threadIdx.x * PAD_STRIDE];

    float s_sq = 0.0f, s_bce = 0.0f, s_bg = 0.0f;
    float s_cnt = 0.0f;

    #pragma unroll
    for (int c = 0; c < CPT; ++c) {
        const int b = c * 5;
        const float p = mx[b];
        const float t = my[b];
        float sq = 0.0f;
        #pragma unroll
        for (int j = 1; j < 5; ++j) {
            const float d = mx[b + j] - my[b + j];
            sq = fmaf(d, d, sq);
        }
        const float lp  = clogf(p);
        const float l1p = clogf(1.0f - p);
        const bool mask = t > THRESH;
        const float bce = -(t * lp + (1.0f - t) * l1p);
        s_sq  += mask ? sq : 0.0f;
        s_bce += mask ? bce : 0.0f;
        s_bg  += mask ? 0.0f : -l1p;
        s_cnt += mask ? 1.0f : 0.0f;
    }

    // ---- Wave-64 butterfly reduce ----
    #pragma unroll
    for (int off = 32; off > 0; off >>= 1) {
        s_sq  += __shfl_down(s_sq,  off, 64);
        s_bce += __shfl_down(s_bce, off, 64);
        s_bg  += __shfl_down(s_bg,  off, 64);
        s_cnt += __shfl_down(s_cnt, off, 64);
    }

    __shared__ float4 r_part[BLOCK / 64];
    const int wave = threadIdx.x >> 6;
    const int lane = threadIdx.x & 63;
    if (lane == 0) r_part[wave] = make_float4(s_sq, s_bce, s_bg, s_cnt);
    __syncthreads();
    if (threadIdx.x == 0) {
        float4 t0 = r_part[0];
        #pragma unroll
        for (int w = 1; w < BLOCK / 64; ++w) {
            t0.x += r_part[w].x; t0.y += r_part[w].y;
            t0.z += r_part[w].z; t0.w += r_part[w].w;
        }
        partials[blockIdx.x] = t0;   // plain store, distinct address per block
    }
}

// Stage 2: one block reduces all per-block partials (double accumulation)
// and computes the final scalar. Also mops up any tail cells directly.
#define FBLOCK 1024
__global__ __launch_bounds__(FBLOCK) void mloss_final(
    const float4* __restrict__ partials, int n_blocks,
    const float* __restrict__ x, const float* __restrict__ y,
    float* __restrict__ out, long long cell_start, long long n_cells)
{
    double s_sq = 0.0, s_bce = 0.0, s_bg = 0.0, s_cnt = 0.0;
    for (int i = threadIdx.x; i < n_blocks; i += FBLOCK) {
        const float4 v = partials[i];
        s_sq += (double)v.x; s_bce += (double)v.y;
        s_bg += (double)v.z; s_cnt += (double)v.w;
    }

    #pragma unroll
    for (int off = 32; off > 0; off >>= 1) {
        s_sq  += __shfl_down(s_sq,  off, 64);
        s_bce += __shfl_down(s_bce, off, 64);
        s_bg  += __shfl_down(s_bg,  off, 64);
        s_cnt += __shfl_down(s_cnt, off, 64);
    }

    __shared__ double r[FBLOCK / 64][4];
    const int wave = threadIdx.x >> 6;
    const int lane = threadIdx.x & 63;
    if (lane == 0) { r[wave][0] = s_sq; r[wave][1] = s_bce; r[wave][2] = s_bg; r[wave][3] = s_cnt; }
    __syncthreads();

    if (threadIdx.x == 0) {
        double t_sq = 0.0, t_bce = 0.0, t_bg = 0.0, face = 0.0;
        #pragma unroll
        for (int w = 0; w < FBLOCK / 64; ++w) {
            t_sq += r[w][0]; t_bce += r[w][1]; t_bg += r[w][2]; face += r[w][3];
        }
        // Tail cells not covered by full stage-1 blocks (none for ref shape).
        for (long long c = cell_start; c < n_cells; ++c) {
            const float p = x[c * 5];
            const float t = y[c * 5];
            float sq = 0.0f;
            for (int j = 1; j < 5; ++j) {
                const float d = x[c * 5 + j] - y[c * 5 + j];
                sq = fmaf(d, d, sq);
            }
            const float lp  = clogf(p);
            const float l1p = clogf(1.0f - p);
            if (t > THRESH) {
                t_sq += (double)sq;
                t_bce += (double)(-(t * lp + (1.0f - t) * l1p));
                face += 1.0;
            } else {
                t_bg += (double)(-l1p);
            }
        }
        const double bg    = (double)n_cells - face;
        const double scale = 1.0 + 1.0 / face;
        *out = (float)(scale * t_sq / (face * 4.0) + scale * t_bce / face + t_bg / bg);
    }
}

extern "C" void kernel_launch(void* const* d_in, const int* in_sizes, int n_in,
                              void* d_out, int out_size, void* d_ws, size_t ws_size,
                              hipStream_t stream) {
    const float* x = (const float*)d_in[0];
    const float* y = (const float*)d_in[1];
    float* out = (float*)d_out;
    float4* partials = (float4*)d_ws;

    const long long n_elems = (long long)in_sizes[0];           // B*N*5
    const long long n_cells = n_elems / 5;                      // B*N
    const long long cells_per_block = (long long)BLOCK * CPT;   // 1024
    const long long full_blocks = n_cells / cells_per_block;    // 5408 for ref shape
    const long long covered = full_blocks * cells_per_block;    // == n_cells here

    mloss_reduce<<<(int)full_blocks, BLOCK, 0, stream>>>(x, y, partials);
    mloss_final<<<1, FBLOCK, 0, stream>>>(partials, (int)full_blocks,
                                          x, y, out, covered, n_cells);
}